// Round 6
// baseline (178.930 us; speedup 1.0000x reference)
//
#include <hip/hip_runtime.h>

// ---------------------------------------------------------------------------
// SocialPooling: pooled = per-person 8x8-grid scatter-add of neighbor hiddens,
// out = relu(pooled @ W + b).  M=B=4096, K=4096, N=1024.
// R6: revert to R4 skeleton (proven: BK=128, 256B/16-slot XOR swizzle, grid
// 512, 32x32x16 MFMA, XCD m-cluster).  NEW: A bypasses LDS -- pool kernel
// writes A in MFMA-fragment order (A'[m/32][k/16][lane][8]) so GEMM loads A
// frags as coalesced global_load_dwordx4 straight to VGPR (L2-resident:
// 4 panels x 1 MB = one XCD's L2).  Only B staged in LDS (16 KB).
// LDS pipe traffic drops ~3x (was the measured bound).
// ---------------------------------------------------------------------------

#define BM 128
#define BN 64
#define BK 128   // shorts (bf16) per K-block

typedef short short8 __attribute__((ext_vector_type(8)));
typedef short short4v __attribute__((ext_vector_type(4)));
typedef float floatx16 __attribute__((ext_vector_type(16)));

__device__ inline short f2bf(float x) {
    union { float f; unsigned u; } v; v.f = x;
    unsigned r = v.u + 0x7fffu + ((v.u >> 16) & 1u);   // round-to-nearest-even
    return (short)(r >> 16);
}

__device__ inline void gload_lds16(const void* g, void* l) {
    __builtin_amdgcn_global_load_lds(
        (const __attribute__((address_space(1))) void*)g,
        (__attribute__((address_space(3))) void*)l,
        16, 0, 0);
}

// ---------------------------------------------------------------------------
// Kernel 1: prep = pool (blocks 0..1023) + W transpose/cast (blocks 1024..2047)
// Pool now writes A' in MFMA-fragment order:
//   A'[(R*256 + T)*512 + hl*256 + (m&31)*8 + j]   (shorts)
// where R=m>>5, k=T*16+hl*8+j.  For k=c*64+d: T=c*4+(d>>4), hl=(d>>3)&1, j=d&7.
// ---------------------------------------------------------------------------
__global__ __launch_bounds__(256) void prep_kernel(
    const float* __restrict__ h,     // (B, 64)
    const float* __restrict__ pos,   // (B, 2)
    short* __restrict__ Afr,         // A' fragment-ordered, B*4096 bf16
    const float* __restrict__ W,     // (K, N)
    short* __restrict__ Wt,          // (N, K) bf16
    int K, int N, int poolBlocks)
{
    __shared__ __align__(16) unsigned char sh[18944];
    const int tid = threadIdx.x;

    if ((int)blockIdx.x < poolBlocks) {
        // ----- pooling: 4 persons of one sequence per block -----
        float* hs = (float*)sh;                          // 64*64 f32 = 16 KB
        float* px = (float*)(sh + 16384);
        float* py = (float*)(sh + 16640);
        unsigned long long* wmask = (unsigned long long*)(sh + 16896); // 4*64

        const int lane = tid & 63;
        const int w    = tid >> 6;
        const int s    = blockIdx.x >> 4;
        const int grp  = blockIdx.x & 15;
        const size_t base = (size_t)s * 64;

        const float4* hv  = (const float4*)(h + base * 64);
        float4*       hsv = (float4*)hs;
        #pragma unroll
        for (int c = 0; c < 4; ++c) hsv[tid + c * 256] = hv[tid + c * 256];
        if (tid < 64) {
            float2 p = ((const float2*)pos)[base + tid];
            px[tid] = p.x; py[tid] = p.y;
        }
        wmask[w * 64 + lane] = 0ull;
        __syncthreads();

        const int i = grp * 4 + w;
        const float tlx = px[i] - 1.0f;
        const float tly = py[i] + 1.0f;
        const float brx = px[i] + 1.0f;
        const float bry = py[i] - 1.0f;

        {   // lane j: neighbor j's cell for person i (wave-local)
            const int j = lane;
            const float ox = px[j], oy = py[j];
            if (ox < brx && ox > tlx && oy < tly && oy > bry && j != i) {
                int cx = (int)floorf((ox - tlx) * 4.0f);
                int cy = (int)floorf((tly - oy) * 4.0f);
                atomicOr(&wmask[w * 64 + cx + cy * 8], 1ull << j);
            }
        }

        const int d = lane;
        const int m = (int)base + i;                   // global person row
        // fragment-order output address (shorts), constant part per lane:
        const size_t pbase = (size_t)(m >> 5) * 131072   // R * 256 * 512
                           + (size_t)(d >> 4) * 512      // T low bits
                           + (size_t)((d >> 3) & 1) * 256
                           + (size_t)(m & 31) * 8
                           + (size_t)(d & 7);
        for (int c = 0; c < 64; ++c) {
            unsigned long long mk = wmask[w * 64 + c];
            float a0 = 0.f, a1 = 0.f;
            while (mk) {
                int j0 = __builtin_ctzll(mk); mk &= mk - 1;
                if (mk) {
                    int j1 = __builtin_ctzll(mk); mk &= mk - 1;
                    a1 += hs[j1 * 64 + d];
                }
                a0 += hs[j0 * 64 + d];
            }
            Afr[pbase + (size_t)c * 2048] = f2bf(a0 + a1);   // c*4*512
        }
    } else {
        // ----- W (K x N f32) -> Wt (N x K bf16), 64x64 tiles -----
        float* t = (float*)sh;                 // [64][65]
        const int bid = blockIdx.x - poolBlocks;
        const int k0 = (bid & 63) * 64;
        const int n0 = (bid >> 6) * 64;

        const int r  = tid >> 4;               // 0..15
        const int cq = (tid & 15) * 4;
        #pragma unroll
        for (int i2 = 0; i2 < 4; ++i2) {
            const int row = r + i2 * 16;
            float4 v = *(const float4*)&W[(size_t)(k0 + row) * N + n0 + cq];
            t[row * 65 + cq + 0] = v.x; t[row * 65 + cq + 1] = v.y;
            t[row * 65 + cq + 2] = v.z; t[row * 65 + cq + 3] = v.w;
        }
        __syncthreads();
        const int nl = tid >> 4;
        const int kq = (tid & 15) * 4;
        #pragma unroll
        for (int i2 = 0; i2 < 4; ++i2) {
            const int n = nl + i2 * 16;
            short4v o;
            o.x = f2bf(t[(kq + 0) * 65 + n]); o.y = f2bf(t[(kq + 1) * 65 + n]);
            o.z = f2bf(t[(kq + 2) * 65 + n]); o.w = f2bf(t[(kq + 3) * 65 + n]);
            *(short4v*)&Wt[(size_t)(n0 + n) * K + k0 + kq] = o;
        }
    }
}

// ---------------------------------------------------------------------------
// Kernel 2: C = relu(A @ Bt^T + bias).  A': fragment-ordered bf16 (direct
// global->VGPR loads, no LDS).  Bt: NxK bf16 staged in LDS (R4-proven path).
// 128x64 block, 4 waves (2x2), wave tile 64x32 = 2x1 of 32x32x16 MFMA.
// ---------------------------------------------------------------------------
__global__ __launch_bounds__(256) void gemm_bias_relu(
    const short* __restrict__ Afr,
    const short* __restrict__ Bt,
    const float* __restrict__ bias,
    float* __restrict__ out,
    int M, int N, int K)
{
    __shared__ __align__(16) short Bs[BN * BK];  // 16 KB

    const int tid  = threadIdx.x;
    const int lane = tid & 63;
    const int wave = tid >> 6;
    const int wr = wave >> 1;          // wave row (m): 0..1
    const int wc = wave & 1;           // wave col (n): 0..1
    const int nl = lane & 31;          // MFMA row/col within 32
    const int hl = lane >> 5;          // K-half
    const int ml = lane & 15;          // swizzle key (= row&15)

    // XCD m-clustered mapping (block b -> XCD b%8): n fastest within XCD.
    const int b  = blockIdx.x;
    const int ib = b >> 3;                          // 0..63
    const int mb = (b & 7) * 4 + (ib >> 4);         // m-block 0..31
    const int n0 = (ib & 15) * BN;

    // B staging (identical to R4's proven conflict-free pattern)
    const int r4   = lane >> 4;        // row within 4-row staging group
    const int slot = lane & 15;        // 16B-granule slot within 256B row
    const short* bg[4];
    #pragma unroll
    for (int c = 0; c < 4; ++c) {
        const int gi = c * 4 + wave;           // 0..15
        const int rl = gi * 4 + r4;            // 0..63
        bg[c] = Bt + (size_t)(n0 + rl) * K + (slot ^ (rl & 15)) * 8;
    }

    // A fragment stream: base for this wave's two 32-row tiles
    const short* a0p = Afr + ((size_t)(mb * 4 + wr * 2) * 256) * 512 + (size_t)lane * 8;
    const short* a1p = a0p + 131072;   // next R page

    floatx16 acc[2];
    #pragma unroll
    for (int mt = 0; mt < 2; ++mt)
        #pragma unroll
        for (int r = 0; r < 16; ++r) acc[mt][r] = 0.f;

    for (int kb = 0; kb < K; kb += BK) {
        if (kb) __syncthreads();
        #pragma unroll
        for (int c = 0; c < 4; ++c) {
            gload_lds16(bg[c], &Bs[(c * 4 + wave) * 512]);
            bg[c] += BK;
        }
        __syncthreads();

        const int tbase = kb >> 4;
        #pragma unroll
        for (int t = 0; t < 8; ++t) {                  // 8 x K=16 steps
            const int koff = (tbase + t) * 512;
            short8 a0 = *(const short8*)(a0p + koff);  // coalesced, L2-hot
            short8 a1 = *(const short8*)(a1p + koff);
            const int g = 2 * t + hl;
            short8 bfr = *(const short8*)&Bs[(wc * 32 + nl) * BK + ((g ^ ml) * 8)];
            acc[0] = __builtin_amdgcn_mfma_f32_32x32x16_bf16(a0, bfr, acc[0], 0, 0, 0);
            acc[1] = __builtin_amdgcn_mfma_f32_32x32x16_bf16(a1, bfr, acc[1], 0, 0, 0);
        }
    }

    // epilogue: bias + relu.  32x32 C/D: col=lane&31, row=(r&3)+8*(r>>2)+4*hl.
    const int gn = n0 + wc * 32 + nl;
    const float bv = bias[gn];
    #pragma unroll
    for (int mt = 0; mt < 2; ++mt) {
        #pragma unroll
        for (int r = 0; r < 16; ++r) {
            const int row32 = (r & 3) + 8 * (r >> 2) + 4 * hl;
            const int gm = mb * BM + wr * 64 + mt * 32 + row32;
            float v = acc[mt][r] + bv;
            out[(size_t)gm * N + gn] = v > 0.f ? v : 0.f;
        }
    }
}

// ---------------------------------------------------------------------------
extern "C" void kernel_launch(void* const* d_in, const int* in_sizes, int n_in,
                              void* d_out, int out_size, void* d_ws, size_t ws_size,
                              hipStream_t stream) {
    const float* h    = (const float*)d_in[0];   // (1, B, 64) f32
    const float* pos  = (const float*)d_in[2];   // (B, 2)     f32
    const float* W    = (const float*)d_in[4];   // (K, N)     f32
    const float* bias = (const float*)d_in[5];   // (N,)       f32

    const int B = in_sizes[0] / 64;       // 4096
    const int N = in_sizes[5];            // 1024
    const int K = 64 * 64;                // GRID^2 * H_DIM = 4096

    short* Afr = (short*)d_ws;                     // B*K bf16 = 32 MB (frag order)
    short* Wt  = Afr + (size_t)B * K;              // N*K bf16 =  8 MB
    float* out = (float*)d_out;

    const int poolBlocks = B / 4;                  // 1024
    const int castBlocks = (K / 64) * (N / 64);    // 1024
    prep_kernel<<<poolBlocks + castBlocks, 256, 0, stream>>>(
        h, pos, Afr, W, Wt, K, N, poolBlocks);
    gemm_bias_relu<<<(B / BM) * (N / BN), 256, 0, stream>>>(
        Afr, Wt, bias, out, B, N, K);
}

// Round 7
// 145.801 us; speedup vs baseline: 1.2272x; 1.2272x over previous
//
#include <hip/hip_runtime.h>

// ---------------------------------------------------------------------------
// SocialPooling: pooled = per-person 8x8-grid scatter-add of neighbor hiddens,
// out = relu(pooled @ W + b).  M=B=4096, K=4096, N=1024.
// R7: R4 skeleton (BK=128, 256B/16-slot XOR swizzle, gload_lds staging, grid
// 512, 32x32x16 MFMA, XCD m-cluster) with 64x128 block of 2 waves, wave tile
// 64x64 (2x2 MFMA): LDS-read bytes/MAC drop 1.5x (measured bottleneck).
// Pool/transpose prep unchanged from R4.
// ---------------------------------------------------------------------------

#define BM 64
#define BN 128
#define BK 128   // shorts (bf16) per K-block

typedef short short8 __attribute__((ext_vector_type(8)));
typedef short short4v __attribute__((ext_vector_type(4)));
typedef float floatx16 __attribute__((ext_vector_type(16)));

__device__ inline short f2bf(float x) {
    union { float f; unsigned u; } v; v.f = x;
    unsigned r = v.u + 0x7fffu + ((v.u >> 16) & 1u);   // round-to-nearest-even
    return (short)(r >> 16);
}

__device__ inline void gload_lds16(const void* g, void* l) {
    __builtin_amdgcn_global_load_lds(
        (const __attribute__((address_space(1))) void*)g,
        (__attribute__((address_space(3))) void*)l,
        16, 0, 0);
}

// ---------------------------------------------------------------------------
// Kernel 1: prep = pool (blocks 0..1023) + W transpose/cast (blocks 1024..2047)
// merged so the two independent stages run concurrently.  (R2/R4-proven.)
// ---------------------------------------------------------------------------
__global__ __launch_bounds__(256) void prep_kernel(
    const float* __restrict__ h,     // (B, 64)
    const float* __restrict__ pos,   // (B, 2)
    short* __restrict__ pooled,      // (B, 4096) bf16
    const float* __restrict__ W,     // (K, N)
    short* __restrict__ Wt,          // (N, K) bf16
    int K, int N, int poolBlocks)
{
    __shared__ __align__(16) unsigned char sh[18944];
    const int tid = threadIdx.x;

    if ((int)blockIdx.x < poolBlocks) {
        // ----- pooling: 4 persons of one sequence per block -----
        float* hs = (float*)sh;                          // 64*64 f32 = 16 KB
        float* px = (float*)(sh + 16384);
        float* py = (float*)(sh + 16640);
        unsigned long long* wmask = (unsigned long long*)(sh + 16896); // 4*64

        const int lane = tid & 63;
        const int w    = tid >> 6;
        const int s    = blockIdx.x >> 4;
        const int grp  = blockIdx.x & 15;
        const size_t base = (size_t)s * 64;

        const float4* hv  = (const float4*)(h + base * 64);
        float4*       hsv = (float4*)hs;
        #pragma unroll
        for (int c = 0; c < 4; ++c) hsv[tid + c * 256] = hv[tid + c * 256];
        if (tid < 64) {
            float2 p = ((const float2*)pos)[base + tid];
            px[tid] = p.x; py[tid] = p.y;
        }
        wmask[w * 64 + lane] = 0ull;
        __syncthreads();

        const int i = grp * 4 + w;
        const float tlx = px[i] - 1.0f;
        const float tly = py[i] + 1.0f;
        const float brx = px[i] + 1.0f;
        const float bry = py[i] - 1.0f;

        {   // lane j: neighbor j's cell for person i (wave-local)
            const int j = lane;
            const float ox = px[j], oy = py[j];
            if (ox < brx && ox > tlx && oy < tly && oy > bry && j != i) {
                int cx = (int)floorf((ox - tlx) * 4.0f);
                int cy = (int)floorf((tly - oy) * 4.0f);
                atomicOr(&wmask[w * 64 + cx + cy * 8], 1ull << j);
            }
        }

        const int d = lane;
        const size_t orow = (base + i) * 4096;
        for (int c = 0; c < 64; ++c) {
            unsigned long long m = wmask[w * 64 + c];
            float a0 = 0.f, a1 = 0.f;
            while (m) {
                int j0 = __builtin_ctzll(m); m &= m - 1;
                if (m) {
                    int j1 = __builtin_ctzll(m); m &= m - 1;
                    a1 += hs[j1 * 64 + d];
                }
                a0 += hs[j0 * 64 + d];
            }
            pooled[orow + c * 64 + d] = f2bf(a0 + a1);
        }
    } else {
        // ----- W (K x N f32) -> Wt (N x K bf16), 64x64 tiles -----
        float* t = (float*)sh;                 // [64][65]
        const int bid = blockIdx.x - poolBlocks;
        const int k0 = (bid & 63) * 64;
        const int n0 = (bid >> 6) * 64;

        const int r  = tid >> 4;               // 0..15
        const int cq = (tid & 15) * 4;
        #pragma unroll
        for (int i2 = 0; i2 < 4; ++i2) {
            const int row = r + i2 * 16;
            float4 v = *(const float4*)&W[(size_t)(k0 + row) * N + n0 + cq];
            t[row * 65 + cq + 0] = v.x; t[row * 65 + cq + 1] = v.y;
            t[row * 65 + cq + 2] = v.z; t[row * 65 + cq + 3] = v.w;
        }
        __syncthreads();
        const int nl = tid >> 4;
        const int kq = (tid & 15) * 4;
        #pragma unroll
        for (int i2 = 0; i2 < 4; ++i2) {
            const int n = nl + i2 * 16;
            short4v o;
            o.x = f2bf(t[(kq + 0) * 65 + n]); o.y = f2bf(t[(kq + 1) * 65 + n]);
            o.z = f2bf(t[(kq + 2) * 65 + n]); o.w = f2bf(t[(kq + 3) * 65 + n]);
            *(short4v*)&Wt[(size_t)(n0 + n) * K + k0 + kq] = o;
        }
    }
}

// ---------------------------------------------------------------------------
// Kernel 2: C = relu(A @ Bt^T + bias).  A: MxK bf16, Bt: NxK bf16.
// 64x128 block, 128 thr = 2 waves side by side, wave tile 64x64 =
// 2x2 of 32x32x16 MFMA.  BK=128 single-buffer 2-barrier loop (R4-proven),
// 256B-row / 16-slot XOR granule swizzle on both stage and read sides
// (identical address structure to R4's measured-0-conflict kernel).
// ---------------------------------------------------------------------------
__global__ __launch_bounds__(128) void gemm_bias_relu(
    const short* __restrict__ A,
    const short* __restrict__ Bt,
    const float* __restrict__ bias,
    float* __restrict__ out,
    int M, int N, int K)
{
    __shared__ __align__(16) short As[BM * BK];  // 16 KB
    __shared__ __align__(16) short Bs[BN * BK];  // 32 KB

    const int tid  = threadIdx.x;
    const int lane = tid & 63;
    const int wave = tid >> 6;          // 0..1 (n-position of wave tile)
    const int nl = lane & 31;           // MFMA row/col within 32
    const int hl = lane >> 5;           // K-half
    const int ml = lane & 15;           // swizzle key (= row&15 of frag rows)

    // XCD m-clustered mapping (block b -> XCD b%8): XCD x owns 8 m-blocks,
    // n fastest (A panel 8 x 512 KB = 4 MB = one XCD L2).
    const int b  = blockIdx.x;
    const int ib = b >> 3;                          // 0..63
    const int mb = (b & 7) * 8 + (ib >> 3);         // m-block 0..63
    const int m0 = mb * BM;
    const int n0 = (ib & 7) * BN;

    // staging: wave-instr covers 4 rows x 16 slots (R4-proven pattern)
    const int r4   = lane >> 4;        // row within 4-row group
    const int slot = lane & 15;        // 16B-granule slot within 256B row

    const short* ag[8];                // As: 16 groups, wave handles c*2+wave
    const short* bg[16];               // Bs: 32 groups
    #pragma unroll
    for (int c = 0; c < 8; ++c) {
        const int gi = c * 2 + wave;           // 0..15
        const int rl = gi * 4 + r4;            // 0..63
        ag[c] = A + (size_t)(m0 + rl) * K + (slot ^ (rl & 15)) * 8;
    }
    #pragma unroll
    for (int c = 0; c < 16; ++c) {
        const int gi = c * 2 + wave;           // 0..31
        const int rl = gi * 4 + r4;            // 0..127
        bg[c] = Bt + (size_t)(n0 + rl) * K + (slot ^ (rl & 15)) * 8;
    }

    floatx16 acc[2][2];                // [m-tile][n-tile]
    #pragma unroll
    for (int i = 0; i < 2; ++i)
        #pragma unroll
        for (int j = 0; j < 2; ++j)
            #pragma unroll
            for (int r = 0; r < 16; ++r) acc[i][j][r] = 0.f;

    for (int kb = 0; kb < K; kb += BK) {
        if (kb) __syncthreads();
        #pragma unroll
        for (int c = 0; c < 8; ++c) {
            gload_lds16(ag[c], &As[(c * 2 + wave) * 512]);
            ag[c] += BK;
        }
        #pragma unroll
        for (int c = 0; c < 16; ++c) {
            gload_lds16(bg[c], &Bs[(c * 2 + wave) * 512]);
            bg[c] += BK;
        }
        __syncthreads();

        #pragma unroll
        for (int t = 0; t < 8; ++t) {                  // 8 x K=16 steps
            const int g  = 2 * t + hl;                 // needed granule
            const int go = (g ^ ml) * 8;               // swizzled offset (shorts)
            short8 a0 = *(const short8*)&As[(nl)      * BK + go];
            short8 a1 = *(const short8*)&As[(32 + nl) * BK + go];
            short8 b0 = *(const short8*)&Bs[(wave * 64 +      nl) * BK + go];
            short8 b1 = *(const short8*)&Bs[(wave * 64 + 32 + nl) * BK + go];
            acc[0][0] = __builtin_amdgcn_mfma_f32_32x32x16_bf16(a0, b0, acc[0][0], 0, 0, 0);
            acc[0][1] = __builtin_amdgcn_mfma_f32_32x32x16_bf16(a0, b1, acc[0][1], 0, 0, 0);
            acc[1][0] = __builtin_amdgcn_mfma_f32_32x32x16_bf16(a1, b0, acc[1][0], 0, 0, 0);
            acc[1][1] = __builtin_amdgcn_mfma_f32_32x32x16_bf16(a1, b1, acc[1][1], 0, 0, 0);
        }
    }

    // epilogue: bias + relu.  32x32 C/D: col=lane&31, row=(r&3)+8*(r>>2)+4*hl.
    #pragma unroll
    for (int jt = 0; jt < 2; ++jt) {
        const int gn = n0 + wave * 64 + jt * 32 + nl;
        const float bv = bias[gn];
        #pragma unroll
        for (int mt = 0; mt < 2; ++mt) {
            #pragma unroll
            for (int r = 0; r < 16; ++r) {
                const int row32 = (r & 3) + 8 * (r >> 2) + 4 * hl;
                const int gm = m0 + mt * 32 + row32;
                float v = acc[mt][jt][r] + bv;
                out[(size_t)gm * N + gn] = v > 0.f ? v : 0.f;
            }
        }
    }
}

// ---------------------------------------------------------------------------
extern "C" void kernel_launch(void* const* d_in, const int* in_sizes, int n_in,
                              void* d_out, int out_size, void* d_ws, size_t ws_size,
                              hipStream_t stream) {
    const float* h    = (const float*)d_in[0];   // (1, B, 64) f32
    const float* pos  = (const float*)d_in[2];   // (B, 2)     f32
    const float* W    = (const float*)d_in[4];   // (K, N)     f32
    const float* bias = (const float*)d_in[5];   // (N,)       f32

    const int B = in_sizes[0] / 64;       // 4096
    const int N = in_sizes[5];            // 1024
    const int K = 64 * 64;                // GRID^2 * H_DIM = 4096

    short* pooled = (short*)d_ws;                  // B*K bf16 = 32 MB
    short* Wt     = pooled + (size_t)B * K;        // N*K bf16 =  8 MB
    float* out    = (float*)d_out;

    const int poolBlocks = B / 4;                  // 1024
    const int castBlocks = (K / 64) * (N / 64);    // 1024
    prep_kernel<<<poolBlocks + castBlocks, 256, 0, stream>>>(
        h, pos, pooled, W, Wt, K, N, poolBlocks);
    gemm_bias_relu<<<(B / BM) * (N / BN), 128, 0, stream>>>(
        pooled, Wt, bias, out, B, N, K);
}

// Round 8
// 137.565 us; speedup vs baseline: 1.3007x; 1.0599x over previous
//
#include <hip/hip_runtime.h>

// ---------------------------------------------------------------------------
// SocialPooling: pooled = per-person 8x8-grid scatter-add of neighbor hiddens,
// out = relu(pooled @ W + b).  M=B=4096, K=4096, N=1024.
// R8: GEMM 128x128 tile, 512 thr = 8 waves (2 K-groups x 2x2 waves of 64x64).
// BK=64 with TWO K-rows packed per 256B LDS row (16 granule slots -> R4's
// proven conflict-free XOR pattern).  Explicit dbuf (64 KB LDS), 1 barrier/
// iter.  8 waves/CU (the measured concurrency requirement).  K-group merge
// via LDS f32 exchange (bank-sweep layout, conflict-free).
// ---------------------------------------------------------------------------

#define BM 128
#define BN 128
#define BK 64    // shorts (bf16) per K-block per buffer

typedef short short8 __attribute__((ext_vector_type(8)));
typedef short short4v __attribute__((ext_vector_type(4)));
typedef float floatx16 __attribute__((ext_vector_type(16)));

__device__ inline short f2bf(float x) {
    union { float f; unsigned u; } v; v.f = x;
    unsigned r = v.u + 0x7fffu + ((v.u >> 16) & 1u);   // round-to-nearest-even
    return (short)(r >> 16);
}

__device__ inline void gload_lds16(const void* g, void* l) {
    __builtin_amdgcn_global_load_lds(
        (const __attribute__((address_space(1))) void*)g,
        (__attribute__((address_space(3))) void*)l,
        16, 0, 0);
}

// ---------------------------------------------------------------------------
// Kernel 1: prep = pool (blocks 0..1023) + W transpose/cast (blocks 1024..2047)
// merged so the two independent stages run concurrently.  (R2/R4-proven.)
// ---------------------------------------------------------------------------
__global__ __launch_bounds__(256) void prep_kernel(
    const float* __restrict__ h,     // (B, 64)
    const float* __restrict__ pos,   // (B, 2)
    short* __restrict__ pooled,      // (B, 4096) bf16
    const float* __restrict__ W,     // (K, N)
    short* __restrict__ Wt,          // (N, K) bf16
    int K, int N, int poolBlocks)
{
    __shared__ __align__(16) unsigned char sh[18944];
    const int tid = threadIdx.x;

    if ((int)blockIdx.x < poolBlocks) {
        // ----- pooling: 4 persons of one sequence per block -----
        float* hs = (float*)sh;                          // 64*64 f32 = 16 KB
        float* px = (float*)(sh + 16384);
        float* py = (float*)(sh + 16640);
        unsigned long long* wmask = (unsigned long long*)(sh + 16896); // 4*64

        const int lane = tid & 63;
        const int w    = tid >> 6;
        const int s    = blockIdx.x >> 4;
        const int grp  = blockIdx.x & 15;
        const size_t base = (size_t)s * 64;

        const float4* hv  = (const float4*)(h + base * 64);
        float4*       hsv = (float4*)hs;
        #pragma unroll
        for (int c = 0; c < 4; ++c) hsv[tid + c * 256] = hv[tid + c * 256];
        if (tid < 64) {
            float2 p = ((const float2*)pos)[base + tid];
            px[tid] = p.x; py[tid] = p.y;
        }
        wmask[w * 64 + lane] = 0ull;
        __syncthreads();

        const int i = grp * 4 + w;
        const float tlx = px[i] - 1.0f;
        const float tly = py[i] + 1.0f;
        const float brx = px[i] + 1.0f;
        const float bry = py[i] - 1.0f;

        {   // lane j: neighbor j's cell for person i (wave-local)
            const int j = lane;
            const float ox = px[j], oy = py[j];
            if (ox < brx && ox > tlx && oy < tly && oy > bry && j != i) {
                int cx = (int)floorf((ox - tlx) * 4.0f);
                int cy = (int)floorf((tly - oy) * 4.0f);
                atomicOr(&wmask[w * 64 + cx + cy * 8], 1ull << j);
            }
        }

        const int d = lane;
        const size_t orow = (base + i) * 4096;
        for (int c = 0; c < 64; ++c) {
            unsigned long long m = wmask[w * 64 + c];
            float a0 = 0.f, a1 = 0.f;
            while (m) {
                int j0 = __builtin_ctzll(m); m &= m - 1;
                if (m) {
                    int j1 = __builtin_ctzll(m); m &= m - 1;
                    a1 += hs[j1 * 64 + d];
                }
                a0 += hs[j0 * 64 + d];
            }
            pooled[orow + c * 64 + d] = f2bf(a0 + a1);
        }
    } else {
        // ----- W (K x N f32) -> Wt (N x K bf16), 64x64 tiles -----
        float* t = (float*)sh;                 // [64][65]
        const int bid = blockIdx.x - poolBlocks;
        const int k0 = (bid & 63) * 64;
        const int n0 = (bid >> 6) * 64;

        const int r  = tid >> 4;               // 0..15
        const int cq = (tid & 15) * 4;
        #pragma unroll
        for (int i2 = 0; i2 < 4; ++i2) {
            const int row = r + i2 * 16;
            float4 v = *(const float4*)&W[(size_t)(k0 + row) * N + n0 + cq];
            t[row * 65 + cq + 0] = v.x; t[row * 65 + cq + 1] = v.y;
            t[row * 65 + cq + 2] = v.z; t[row * 65 + cq + 3] = v.w;
        }
        __syncthreads();
        const int nl = tid >> 4;
        const int kq = (tid & 15) * 4;
        #pragma unroll
        for (int i2 = 0; i2 < 4; ++i2) {
            const int n = nl + i2 * 16;
            short4v o;
            o.x = f2bf(t[(kq + 0) * 65 + n]); o.y = f2bf(t[(kq + 1) * 65 + n]);
            o.z = f2bf(t[(kq + 2) * 65 + n]); o.w = f2bf(t[(kq + 3) * 65 + n]);
            *(short4v*)&Wt[(size_t)(n0 + n) * K + k0 + kq] = o;
        }
    }
}

// ---------------------------------------------------------------------------
// Kernel 2: C = relu(A @ Bt^T + bias).  A: MxK bf16, Bt: NxK bf16.
// 128x128 block, 512 thr = 8 waves: kg = wave>>2 splits K (each kg owns 32 of
// each 64-K block); 2x2 waves of 64x64 (2x2 of 32x32x16 MFMA).
// LDS row packing: orig rows 2R,2R+1 (64 shorts each) share LDS row R
// (256 B, 16 slots); slot = (row&1)*8 + (granule ^ (R&7)).  Same 16-slot
// XOR structure as R4's measured-0-conflict kernel.  Explicit dbuf,
// one barrier per iter.  K-group merge via LDS f32 exchange.
// ---------------------------------------------------------------------------
__global__ __launch_bounds__(512, 2) void gemm_bias_relu(
    const short* __restrict__ A,
    const short* __restrict__ Bt,
    const float* __restrict__ bias,
    float* __restrict__ out,
    int M, int N, int K)
{
    // [buf][mat][64 LDS-rows * 128 shorts] = 2*2*16 KB = 64 KB
    __shared__ __align__(16) short smem[2][2][64 * 128];

    const int tid  = threadIdx.x;
    const int lane = tid & 63;
    const int wave = tid >> 6;          // 0..7
    const int kg = wave >> 2;           // K-group 0..1
    const int w4 = wave & 3;
    const int wr = w4 >> 1;             // wave row in 2x2
    const int wc = w4 & 1;              // wave col
    const int nl = lane & 31;           // MFMA row/col within 32
    const int hl = lane >> 5;           // K-half of the 16-K step
    const int key = (nl >> 1) & 7;      // read-side swizzle key (= R&7)

    // XCD m-clustered mapping (block b -> XCD b%8): XCD x owns m-blocks
    // 4x..4x+3 (4 x 1MB A panels = its L2), n fastest.
    const int b  = blockIdx.x;
    const int ib = b >> 3;                          // 0..31
    const int m0 = ((b & 7) * 4 + (ib >> 3)) * BM;  // m-block 0..31
    const int n0 = (ib & 7) * BN;                   // n-block 0..7

    // staging: instr c' = c*8+wave covers LDS rows 4c'..4c'+3 (= orig rows
    // 8c'..8c'+7).  lane l -> LDS row R=4c'+(l>>4), slot s=l&15,
    // orig row rl = 2R+(s>>3), granule g = (s&7)^(R&7).
    const short* ag[2];
    const short* bg[2];
    int cpr[2];
    #pragma unroll
    for (int c = 0; c < 2; ++c) {
        const int cp = c * 8 + wave;            // 0..15
        const int R  = cp * 4 + (lane >> 4);
        const int s  = lane & 15;
        const int rl = 2 * R + (s >> 3);
        const int g  = (s & 7) ^ (R & 7);
        cpr[c] = cp;
        ag[c] = A  + (size_t)(m0 + rl) * K + g * 8;
        bg[c] = Bt + (size_t)(n0 + rl) * K + g * 8;
    }

    floatx16 acc[2][2];                 // [mt][jt]
    #pragma unroll
    for (int i = 0; i < 2; ++i)
        #pragma unroll
        for (int j = 0; j < 2; ++j)
            #pragma unroll
            for (int r = 0; r < 16; ++r) acc[i][j][r] = 0.f;

    // prologue: stage first K-block into buf 0
    #pragma unroll
    for (int c = 0; c < 2; ++c) {
        gload_lds16(ag[c], &smem[0][0][cpr[c] * 512]);
        gload_lds16(bg[c], &smem[0][1][cpr[c] * 512]);
        ag[c] += BK; bg[c] += BK;
    }
    __syncthreads();

    const int nIter = K / BK;           // 64
    for (int it = 0; it < nIter; ++it) {
        const int bu = it & 1;
        if (it + 1 < nIter) {           // prefetch next block into bu^1
            #pragma unroll
            for (int c = 0; c < 2; ++c) {
                gload_lds16(ag[c], &smem[bu ^ 1][0][cpr[c] * 512]);
                gload_lds16(bg[c], &smem[bu ^ 1][1][cpr[c] * 512]);
                ag[c] += BK; bg[c] += BK;
            }
        }
        // compute this kg's half of the K-block: t_global = kg*2 + t
        #pragma unroll
        for (int t = 0; t < 2; ++t) {
            const int g = kg * 4 + 2 * t + hl;      // granule 0..7
            const int so = ((g ^ key) & 7) * 8;     // swizzled granule offset
            short8 af[2], bf[2];
            #pragma unroll
            for (int mt = 0; mt < 2; ++mt) {
                const int R = wr * 32 + mt * 16 + (nl >> 1);
                af[mt] = *(const short8*)&smem[bu][0][R * 128 + (nl & 1) * 64 + so];
            }
            #pragma unroll
            for (int jt = 0; jt < 2; ++jt) {
                const int R = wc * 32 + jt * 16 + (nl >> 1);
                bf[jt] = *(const short8*)&smem[bu][1][R * 128 + (nl & 1) * 64 + so];
            }
            #pragma unroll
            for (int mt = 0; mt < 2; ++mt)
                #pragma unroll
                for (int jt = 0; jt < 2; ++jt)
                    acc[mt][jt] = __builtin_amdgcn_mfma_f32_32x32x16_bf16(
                        af[mt], bf[jt], acc[mt][jt], 0, 0, 0);
        }
        __syncthreads();   // prefetch drain overlapped with compute above
    }

    // K-group merge: kg1 writes its partials to LDS, kg0 adds + epilogue.
    // [row][col] f32 64x64 per wave-pair region: writes/reads sweep banks.
    float* xp = (float*)smem + w4 * 4096;   // 16 KB per region, 64 KB total
    if (kg == 1) {
        #pragma unroll
        for (int mt = 0; mt < 2; ++mt)
            #pragma unroll
            for (int jt = 0; jt < 2; ++jt)
                #pragma unroll
                for (int r = 0; r < 16; ++r) {
                    const int row = mt * 32 + (r & 3) + 8 * (r >> 2) + 4 * hl;
                    const int col = jt * 32 + nl;
                    xp[row * 64 + col] = acc[mt][jt][r];
                }
    }
    __syncthreads();
    if (kg == 0) {
        #pragma unroll
        for (int jt = 0; jt < 2; ++jt) {
            const int gn = n0 + wc * 64 + jt * 32 + nl;
            const float bv = bias[gn];
            #pragma unroll
            for (int mt = 0; mt < 2; ++mt)
                #pragma unroll
                for (int r = 0; r < 16; ++r) {
                    const int row = mt * 32 + (r & 3) + 8 * (r >> 2) + 4 * hl;
                    float v = acc[mt][jt][r] + xp[row * 64 + jt * 32 + nl] + bv;
                    const int gm = m0 + wr * 64 + row;
                    out[(size_t)gm * N + gn] = v > 0.f ? v : 0.f;
                }
        }
    }
}

// ---------------------------------------------------------------------------
extern "C" void kernel_launch(void* const* d_in, const int* in_sizes, int n_in,
                              void* d_out, int out_size, void* d_ws, size_t ws_size,
                              hipStream_t stream) {
    const float* h    = (const float*)d_in[0];   // (1, B, 64) f32
    const float* pos  = (const float*)d_in[2];   // (B, 2)     f32
    const float* W    = (const float*)d_in[4];   // (K, N)     f32
    const float* bias = (const float*)d_in[5];   // (N,)       f32

    const int B = in_sizes[0] / 64;       // 4096
    const int N = in_sizes[5];            // 1024
    const int K = 64 * 64;                // GRID^2 * H_DIM = 4096

    short* pooled = (short*)d_ws;                  // B*K bf16 = 32 MB
    short* Wt     = pooled + (size_t)B * K;        // N*K bf16 =  8 MB
    float* out    = (float*)d_out;

    const int poolBlocks = B / 4;                  // 1024
    const int castBlocks = (K / 64) * (N / 64);    // 1024
    prep_kernel<<<poolBlocks + castBlocks, 256, 0, stream>>>(
        h, pos, pooled, W, Wt, K, N, poolBlocks);
    gemm_bias_relu<<<(B / BM) * (N / BN), 512, 0, stream>>>(
        pooled, Wt, bias, out, B, N, K);
}

// Round 9
// 130.342 us; speedup vs baseline: 1.3728x; 1.0554x over previous
//
#include <hip/hip_runtime.h>

// ---------------------------------------------------------------------------
// SocialPooling: pooled = per-person 8x8-grid scatter-add of neighbor hiddens,
// out = relu(pooled @ W + b).  M=B=4096, K=4096, N=1024.
// R9: GEMM = R4 verbatim (best of 6 structural variants: 128x64 tile, BK=128,
// single-buffer 2-barrier loop, 256B/16-slot XOR swizzle, 32x32x16 MFMA,
// XCD m-cluster, grid 512 = 2 blocks/CU).  Pool phase-C: 2 cells/wave with
// float2 dim-pairs -- half the walk+store instructions, 256B stores.
// ---------------------------------------------------------------------------

#define BM 128
#define BN 64
#define BK 128   // shorts (bf16) per K-block

typedef short short8 __attribute__((ext_vector_type(8)));
typedef short short4v __attribute__((ext_vector_type(4)));
typedef float floatx16 __attribute__((ext_vector_type(16)));

__device__ inline short f2bf(float x) {
    union { float f; unsigned u; } v; v.f = x;
    unsigned r = v.u + 0x7fffu + ((v.u >> 16) & 1u);   // round-to-nearest-even
    return (short)(r >> 16);
}

__device__ inline void gload_lds16(const void* g, void* l) {
    __builtin_amdgcn_global_load_lds(
        (const __attribute__((address_space(1))) void*)g,
        (__attribute__((address_space(3))) void*)l,
        16, 0, 0);
}

// ---------------------------------------------------------------------------
// Kernel 1: prep = pool (blocks 0..1023) + W transpose/cast (blocks 1024..2047)
// merged so the two independent stages run concurrently.
// ---------------------------------------------------------------------------
__global__ __launch_bounds__(256) void prep_kernel(
    const float* __restrict__ h,     // (B, 64)
    const float* __restrict__ pos,   // (B, 2)
    short* __restrict__ pooled,      // (B, 4096) bf16
    const float* __restrict__ W,     // (K, N)
    short* __restrict__ Wt,          // (N, K) bf16
    int K, int N, int poolBlocks)
{
    __shared__ __align__(16) unsigned char sh[18944];
    const int tid = threadIdx.x;

    if ((int)blockIdx.x < poolBlocks) {
        // ----- pooling: 4 persons of one sequence per block -----
        float* hs = (float*)sh;                          // 64*64 f32 = 16 KB
        float* px = (float*)(sh + 16384);
        float* py = (float*)(sh + 16640);
        unsigned long long* wmask = (unsigned long long*)(sh + 16896); // 4*64

        const int lane = tid & 63;
        const int w    = tid >> 6;
        const int s    = blockIdx.x >> 4;
        const int grp  = blockIdx.x & 15;
        const size_t base = (size_t)s * 64;

        const float4* hv  = (const float4*)(h + base * 64);
        float4*       hsv = (float4*)hs;
        #pragma unroll
        for (int c = 0; c < 4; ++c) hsv[tid + c * 256] = hv[tid + c * 256];
        if (tid < 64) {
            float2 p = ((const float2*)pos)[base + tid];
            px[tid] = p.x; py[tid] = p.y;
        }
        wmask[w * 64 + lane] = 0ull;
        __syncthreads();

        const int i = grp * 4 + w;
        const float tlx = px[i] - 1.0f;
        const float tly = py[i] + 1.0f;
        const float brx = px[i] + 1.0f;
        const float bry = py[i] - 1.0f;

        {   // lane j: neighbor j's cell for person i (wave-local)
            const int j = lane;
            const float ox = px[j], oy = py[j];
            if (ox < brx && ox > tlx && oy < tly && oy > bry && j != i) {
                int cx = (int)floorf((ox - tlx) * 4.0f);
                int cy = (int)floorf((tly - oy) * 4.0f);
                atomicOr(&wmask[w * 64 + cx + cy * 8], 1ull << j);
            }
        }

        // phase C: 2 cells per wave-pass; lane half picks the cell, each lane
        // sums a float2 dim-pair.  Masks are uniform within each half (one
        // person per wave) so the walk has only 2-way divergence.
        const int half = lane >> 5;            // cell offset 0/1
        const int d0   = (lane & 31) * 2;      // dim pair
        const size_t orow = (base + i) * 4096;
        unsigned short* pooledU = (unsigned short*)pooled;
        for (int c = 0; c < 64; c += 2) {
            unsigned long long m = wmask[w * 64 + c + half];
            float ax = 0.f, ay = 0.f;
            while (m) {
                int j0 = __builtin_ctzll(m); m &= m - 1;
                float2 hv2 = *(const float2*)&hs[j0 * 64 + d0];
                ax += hv2.x; ay += hv2.y;
            }
            unsigned pk = ((unsigned)(unsigned short)f2bf(ay) << 16)
                        |  (unsigned short)f2bf(ax);
            *(unsigned*)&pooledU[orow + (size_t)(c + half) * 64 + d0] = pk;
        }
    } else {
        // ----- W (K x N f32) -> Wt (N x K bf16), 64x64 tiles -----
        float* t = (float*)sh;                 // [64][65]
        const int bid = blockIdx.x - poolBlocks;
        const int k0 = (bid & 63) * 64;
        const int n0 = (bid >> 6) * 64;

        const int r  = tid >> 4;               // 0..15
        const int cq = (tid & 15) * 4;
        #pragma unroll
        for (int i2 = 0; i2 < 4; ++i2) {
            const int row = r + i2 * 16;
            float4 v = *(const float4*)&W[(size_t)(k0 + row) * N + n0 + cq];
            t[row * 65 + cq + 0] = v.x; t[row * 65 + cq + 1] = v.y;
            t[row * 65 + cq + 2] = v.z; t[row * 65 + cq + 3] = v.w;
        }
        __syncthreads();
        const int nl = tid >> 4;
        const int kq = (tid & 15) * 4;
        #pragma unroll
        for (int i2 = 0; i2 < 4; ++i2) {
            const int n = nl + i2 * 16;
            short4v o;
            o.x = f2bf(t[(kq + 0) * 65 + n]); o.y = f2bf(t[(kq + 1) * 65 + n]);
            o.z = f2bf(t[(kq + 2) * 65 + n]); o.w = f2bf(t[(kq + 3) * 65 + n]);
            *(short4v*)&Wt[(size_t)(n0 + n) * K + k0 + kq] = o;
        }
    }
}

// ---------------------------------------------------------------------------
// Kernel 2 (R4 verbatim): C = relu(A @ Bt^T + bias).  A: MxK, Bt: NxK bf16.
// 128x64 block tile, BK=128, 4 waves (2x2), wave tile 64x32 = 2x1 of 32x32x16
// MFMA.  global_load_lds(16B) staging with XOR granule swizzle (0 conflicts
// measured).  XCD m-clustered block mapping.
// ---------------------------------------------------------------------------
__global__ __launch_bounds__(256) void gemm_bias_relu(
    const short* __restrict__ A,
    const short* __restrict__ Bt,
    const float* __restrict__ bias,
    float* __restrict__ out,
    int M, int N, int K)
{
    __shared__ __align__(16) short As[BM * BK];  // 32 KB
    __shared__ __align__(16) short Bs[BN * BK];  // 16 KB

    const int tid  = threadIdx.x;
    const int lane = tid & 63;
    const int wave = tid >> 6;
    const int wr = wave >> 1;          // wave row (m): 0..1
    const int wc = wave & 1;           // wave col (n): 0..1
    const int nl = lane & 31;          // MFMA row/col within 32
    const int hl = lane >> 5;          // K-half
    const int ml = lane & 15;          // swizzle key (= row&15)

    // XCD m-clustered mapping (dispatch: block b -> XCD b%8)
    const int b  = blockIdx.x;
    const int ib = b >> 3;
    const int m0 = ((b & 7) * 4 + (ib >> 4)) * BM;
    const int n0 = (ib & 15) * BN;

    const int r4   = lane >> 4;        // row within 4-row staging group
    const int slot = lane & 15;        // 16B-granule slot within 256B row

    const short* ag[8];
    const short* bg[4];
    #pragma unroll
    for (int c = 0; c < 8; ++c) {
        const int gi = c * 4 + wave;           // 0..31
        const int rl = gi * 4 + r4;            // 0..127
        ag[c] = A + (size_t)(m0 + rl) * K + (slot ^ (rl & 15)) * 8;
    }
    #pragma unroll
    for (int c = 0; c < 4; ++c) {
        const int gi = c * 4 + wave;           // 0..15
        const int rl = gi * 4 + r4;            // 0..63
        bg[c] = Bt + (size_t)(n0 + rl) * K + (slot ^ (rl & 15)) * 8;
    }

    floatx16 acc[2];
    #pragma unroll
    for (int mt = 0; mt < 2; ++mt)
        #pragma unroll
        for (int r = 0; r < 16; ++r) acc[mt][r] = 0.f;

    for (int kb = 0; kb < K; kb += BK) {
        if (kb) __syncthreads();
        #pragma unroll
        for (int c = 0; c < 8; ++c) {
            gload_lds16(ag[c], &As[(c * 4 + wave) * 512]);
            ag[c] += BK;
        }
        #pragma unroll
        for (int c = 0; c < 4; ++c) {
            gload_lds16(bg[c], &Bs[(c * 4 + wave) * 512]);
            bg[c] += BK;
        }
        __syncthreads();

        #pragma unroll
        for (int t = 0; t < 8; ++t) {                  // 8 x K=16 steps
            const int g  = 2 * t + hl;                 // needed granule
            short8 a0 = *(const short8*)&As[(wr * 64 +      nl) * BK + ((g ^ ml) * 8)];
            short8 a1 = *(const short8*)&As[(wr * 64 + 32 + nl) * BK + ((g ^ ml) * 8)];
            short8 bfr = *(const short8*)&Bs[(wc * 32 +     nl) * BK + ((g ^ ml) * 8)];
            acc[0] = __builtin_amdgcn_mfma_f32_32x32x16_bf16(a0, bfr, acc[0], 0, 0, 0);
            acc[1] = __builtin_amdgcn_mfma_f32_32x32x16_bf16(a1, bfr, acc[1], 0, 0, 0);
        }
    }

    // epilogue: bias + relu.  32x32 C/D: col=lane&31, row=(r&3)+8*(r>>2)+4*hl.
    const int gn = n0 + wc * 32 + nl;
    const float bv = bias[gn];
    #pragma unroll
    for (int mt = 0; mt < 2; ++mt) {
        #pragma unroll
        for (int r = 0; r < 16; ++r) {
            const int row32 = (r & 3) + 8 * (r >> 2) + 4 * hl;
            const int gm = m0 + wr * 64 + mt * 32 + row32;
            float v = acc[mt][r] + bv;
            out[(size_t)gm * N + gn] = v > 0.f ? v : 0.f;
        }
    }
}

// ---------------------------------------------------------------------------
extern "C" void kernel_launch(void* const* d_in, const int* in_sizes, int n_in,
                              void* d_out, int out_size, void* d_ws, size_t ws_size,
                              hipStream_t stream) {
    const float* h    = (const float*)d_in[0];   // (1, B, 64) f32
    const float* pos  = (const float*)d_in[2];   // (B, 2)     f32
    const float* W    = (const float*)d_in[4];   // (K, N)     f32
    const float* bias = (const float*)d_in[5];   // (N,)       f32

    const int B = in_sizes[0] / 64;       // 4096
    const int N = in_sizes[5];            // 1024
    const int K = 64 * 64;                // GRID^2 * H_DIM = 4096

    short* pooled = (short*)d_ws;                  // B*K bf16 = 32 MB
    short* Wt     = pooled + (size_t)B * K;        // N*K bf16 =  8 MB
    float* out    = (float*)d_out;

    const int poolBlocks = B / 4;                  // 1024
    const int castBlocks = (K / 64) * (N / 64);    // 1024
    prep_kernel<<<poolBlocks + castBlocks, 256, 0, stream>>>(
        h, pos, pooled, W, Wt, K, N, poolBlocks);
    gemm_bias_relu<<<(B / BM) * (N / BN), 256, 0, stream>>>(
        pooled, Wt, bias, out, B, N, K);
}